// Round 2
// baseline (17210.620 us; speedup 1.0000x reference)
//
#include <hip/hip_runtime.h>
#include <cstdint>
#include <cstdio>

// Problem constants (shapes from setup_inputs)
#define DIMF 128
#define JAX_PARTITIONABLE 1   // modern JAX default (>=0.4.36). Flip to 0 if masks mismatch.

// ---------------- JAX threefry2x32 (exact) ----------------
__host__ __device__ __forceinline__ void tf2x32(uint32_t k0, uint32_t k1,
                                                uint32_t x0, uint32_t x1,
                                                uint32_t& o0, uint32_t& o1) {
  uint32_t ks2 = k0 ^ k1 ^ 0x1BD11BDAu;
  x0 += k0; x1 += k1;
#define TFR(r) { x0 += x1; x1 = (x1 << (r)) | (x1 >> (32 - (r))); x1 ^= x0; }
  TFR(13) TFR(15) TFR(26) TFR(6)
  x0 += k1;  x1 += ks2 + 1u;
  TFR(17) TFR(29) TFR(16) TFR(24)
  x0 += ks2; x1 += k0 + 2u;
  TFR(13) TFR(15) TFR(26) TFR(6)
  x0 += k0;  x1 += k1 + 3u;
  TFR(17) TFR(29) TFR(16) TFR(24)
  x0 += k1;  x1 += ks2 + 4u;
  TFR(13) TFR(15) TFR(26) TFR(6)
  x0 += ks2; x1 += k0 + 5u;
#undef TFR
  o0 = x0; o1 = x1;
}

// ---------------- dropout(0.2) + relu, JAX-bit-exact mask ----------------
__global__ __launch_bounds__(256) void k_drop_relu(const float* __restrict__ in,
                                                   float* __restrict__ out,
                                                   int size, uint32_t k0, uint32_t k1) {
  int i = blockIdx.x * 256 + threadIdx.x;
  if (i >= size) return;
  uint32_t o0, o1, bits;
#if JAX_PARTITIONABLE
  tf2x32(k0, k1, 0u, (uint32_t)i, o0, o1);
  bits = o0 ^ o1;
#else
  uint32_t half = (uint32_t)(size / 2);
  uint32_t j = (uint32_t)i < half ? (uint32_t)i : (uint32_t)i - half;
  tf2x32(k0, k1, j, j + half, o0, o1);
  bits = ((uint32_t)i < half) ? o0 : o1;
#endif
  float u = __uint_as_float((bits >> 9) | 0x3f800000u) - 1.0f;
  float x = in[i];
  float y = (u < 0.8f) ? (x / 0.8f) : 0.0f;   // division, matching jnp exactly
  out[i] = fmaxf(y, 0.0f);
}

// ---------------- per-dst degree count ----------------
__global__ __launch_bounds__(256) void k_count(const int* __restrict__ ei,
                                               float* __restrict__ cnt, int E) {
  int e = blockIdx.x * 256 + threadIdx.x;
  if (e < E) unsafeAtomicAdd(cnt + ei[E + e], 1.0f);
}

__global__ __launch_bounds__(256) void k_inv(const float* __restrict__ cnt,
                                             float* __restrict__ inv, int n) {
  int i = blockIdx.x * 256 + threadIdx.x;
  if (i < n) inv[i] = 1.0f / fmaxf(cnt[i], 1.0f);
}

// ---------------- edge scatter-add (32 lanes per edge, float4) ----------------
__global__ __launch_bounds__(256) void k_scatter(const float* __restrict__ feat,
                                                 const int* __restrict__ ei,
                                                 float* __restrict__ aggr, int E) {
  int gid = blockIdx.x * 256 + threadIdx.x;
  int e = gid >> 5, lane = gid & 31;
  if (e >= E) return;
  int s = ei[e];
  int d = ei[E + e];
  float4 v = *(const float4*)(feat + (size_t)s * DIMF + lane * 4);
  float* p = aggr + (size_t)d * DIMF + lane * 4;
  unsafeAtomicAdd(p + 0, v.x);
  unsafeAtomicAdd(p + 1, v.y);
  unsafeAtomicAdd(p + 2, v.z);
  unsafeAtomicAdd(p + 3, v.w);
}

// ---------------- combined-weight precompute: C = A0@B0 (+ A1@B1) ----------------
struct WDesc { const float* A0; const float* B0; const float* A1; const float* B1; float* C; };
struct WPack { WDesc d[10]; };

__global__ __launch_bounds__(256) void k_wprec(WPack p) {
  const WDesc d = p.d[blockIdx.x >> 2];
  const int rt = blockIdx.x & 3;            // 32-row tile
  __shared__ float A_s[32 * 128];
  const int t = threadIdx.x;
  const int c = t & 127, rh = t >> 7;       // rh in {0,1}
  float acc[16];
#pragma unroll
  for (int i = 0; i < 16; ++i) acc[i] = 0.f;
  for (int pass = 0; pass < 2; ++pass) {
    const float* A = pass ? d.A1 : d.A0;
    const float* B = pass ? d.B1 : d.B0;
    if (!A) break;
    __syncthreads();
#pragma unroll
    for (int j = 0; j < 4; ++j) {
      int f = t + 256 * j;                  // float4 index, 1024 total
      *(float4*)(A_s + 4 * f) = *(const float4*)(A + (size_t)rt * 32 * 128 + 4 * f);
    }
    __syncthreads();
    for (int k = 0; k < 128; ++k) {
      float b = B[(size_t)k * 128 + c];
#pragma unroll
      for (int i = 0; i < 16; ++i)
        acc[i] += A_s[(rh + 2 * i) * 128 + k] * b;
    }
  }
#pragma unroll
  for (int i = 0; i < 16; ++i)
    d.C[(size_t)(rt * 32 + rh + 2 * i) * 128 + c] = acc[i];
}

// ---------------- combined bias: cb = bn@Wu_hi + bs@Wu_lo + bu (summed per dst type) ----------------
__global__ __launch_bounds__(256) void k_bias(const float* __restrict__ bn,
                                              const float* __restrict__ bs,
                                              const float* __restrict__ bu,
                                              const float* __restrict__ Wu,
                                              float* __restrict__ cbA, float* __restrict__ cbB) {
  int t = threadIdx.x;
  int h = t & 127;
  if (t < 128) {
    float acc = bu[0 * 128 + h] + bu[2 * 128 + h];
    for (int j = 0; j < 128; ++j) {
      acc += bn[0 * 128 + j] * Wu[(size_t)0 * 32768 + (size_t)j * 128 + h];
      acc += bs[0 * 128 + j] * Wu[(size_t)0 * 32768 + 16384 + (size_t)j * 128 + h];
      acc += bn[2 * 128 + j] * Wu[(size_t)2 * 32768 + (size_t)j * 128 + h];
      acc += bs[2 * 128 + j] * Wu[(size_t)2 * 32768 + 16384 + (size_t)j * 128 + h];
    }
    cbA[h] = acc;
  } else {
    float acc = bu[128 + h];
    for (int j = 0; j < 128; ++j) {
      acc += bn[128 + j] * Wu[(size_t)1 * 32768 + (size_t)j * 128 + h];
      acc += bs[128 + j] * Wu[(size_t)1 * 32768 + 16384 + (size_t)j * 128 + h];
    }
    cbB[h] = acc;
  }
}

// ---------------- fused multi-term matmul: out = sum_t (s_t * sc_t) @ W_t + bias ----------------
// 64 rows x 128 cols per block, 256 threads, K = 128 per term. In-place safe
// (out may alias any s_t): each block only reads/writes its own 64 rows.
template <int NT>
__global__ __launch_bounds__(256) void k_mm(
    const float* __restrict__ s0, const float* __restrict__ sc0,
    const float* __restrict__ s1, const float* __restrict__ sc1,
    const float* __restrict__ s2, const float* __restrict__ sc2,
    const float* __restrict__ w0, const float* __restrict__ w1, const float* __restrict__ w2,
    const float* __restrict__ bias,
    float* __restrict__ out, int nrows) {
  __shared__ float a_s[64 * 36];     // stride 36: conflict-free (4*rp+k) banks
  __shared__ float w_s[32 * 128];
  const int t = threadIdx.x;
  const int r0 = blockIdx.x * 64;
  const int cg = t & 7;              // col group: cols {4cg+32q}
  const int rp = t >> 3;             // 0..31 -> rows rp, rp+32
  float4 acc[2][4];
#pragma unroll
  for (int q = 0; q < 4; ++q) {
    float4 b = *(const float4*)(bias + cg * 4 + 32 * q);
    acc[0][q] = b; acc[1][q] = b;
  }
#pragma unroll
  for (int term = 0; term < NT; ++term) {
    const float* src   = term == 0 ? s0 : (term == 1 ? s1 : s2);
    const float* scale = term == 0 ? sc0 : (term == 1 ? sc1 : sc2);
    const float* Wt    = term == 0 ? w0 : (term == 1 ? w1 : w2);
    for (int kc = 0; kc < 4; ++kc) {
      __syncthreads();
      { // stage A tile (64 x 32), applying 1/deg scale if present
        int fq = t & 7, row = t >> 3;
#pragma unroll
        for (int h = 0; h < 2; ++h) {
          int r = row + 32 * h;
          int gr = r0 + r;
          float4 v = make_float4(0.f, 0.f, 0.f, 0.f);
          if (gr < nrows) {
            v = *(const float4*)(src + (size_t)gr * 128 + kc * 32 + fq * 4);
            if (scale) { float s = scale[gr]; v.x *= s; v.y *= s; v.z *= s; v.w *= s; }
          }
          *(float4*)(a_s + r * 36 + fq * 4) = v;
        }
      }
      { // stage W tile (32 x 128)
#pragma unroll
        for (int j = 0; j < 4; ++j) {
          int f = t + 256 * j;
          int kr = f >> 5, c4 = (f & 31) << 2;
          *(float4*)(w_s + kr * 128 + c4) = *(const float4*)(Wt + (size_t)(kc * 32 + kr) * 128 + c4);
        }
      }
      __syncthreads();
#pragma unroll 8
      for (int k = 0; k < 32; ++k) {
        float a0 = a_s[rp * 36 + k];
        float a1 = a_s[(rp + 32) * 36 + k];
#pragma unroll
        for (int q = 0; q < 4; ++q) {
          float4 w = *(const float4*)(w_s + k * 128 + cg * 4 + 32 * q);
          acc[0][q].x += a0 * w.x; acc[0][q].y += a0 * w.y;
          acc[0][q].z += a0 * w.z; acc[0][q].w += a0 * w.w;
          acc[1][q].x += a1 * w.x; acc[1][q].y += a1 * w.y;
          acc[1][q].z += a1 * w.z; acc[1][q].w += a1 * w.w;
        }
      }
    }
  }
#pragma unroll
  for (int h = 0; h < 2; ++h) {
    int gr = r0 + rp + 32 * h;
    if (gr < nrows) {
#pragma unroll
      for (int q = 0; q < 4; ++q)
        *(float4*)(out + (size_t)gr * 128 + cg * 4 + 32 * q) = acc[h][q];
    }
  }
}

// ---------------- host driver ----------------
extern "C" void kernel_launch(void* const* d_in, const int* in_sizes, int n_in,
                              void* d_out, int out_size, void* d_ws, size_t ws_size,
                              hipStream_t stream) {
  const float* xA  = (const float*)d_in[0];
  const float* xB  = (const float*)d_in[1];
  const int*   ei0 = (const int*)d_in[2];
  const int*   ei1 = (const int*)d_in[3];
  const int*   ei2 = (const int*)d_in[4];
  const float* Wn1 = (const float*)d_in[5];
  const float* Ws1 = (const float*)d_in[6];
  const float* Wu1 = (const float*)d_in[7];
  const float* Wn2 = (const float*)d_in[8];
  const float* Ws2 = (const float*)d_in[9];
  const float* Wu2 = (const float*)d_in[10];
  const float* bn1 = (const float*)d_in[11];
  const float* bs1 = (const float*)d_in[12];
  const float* bu1 = (const float*)d_in[13];
  const float* bn2 = (const float*)d_in[14];
  const float* bs2 = (const float*)d_in[15];
  const float* bu2 = (const float*)d_in[16];

  const int n  = in_sizes[0] / DIMF;        // 100000
  const int E  = in_sizes[2] / 2;           // 1600000
  const size_t nh = (size_t)n * DIMF;
  const size_t MS = 128 * 128;

  float* ws   = (float*)d_ws;
  float* buf0 = ws;                 // hA / oA1 / h2A
  float* buf1 = buf0 + nh;          // hB / aggr scratch
  float* buf2 = buf1 + nh;          // aggr1 / oB1 / h2B
  float* buf3 = buf2 + nh;          // aggr2
  float* cnt  = buf3 + nh;          // [3n]
  float* inv  = cnt + 3 * (size_t)n;  // [3n]
  float* wts  = inv + 3 * (size_t)n;
  float* Cn0_1 = wts + 0 * MS, *Cn1_1 = wts + 1 * MS, *Cn2_1 = wts + 2 * MS;
  float* CsA1 = wts + 3 * MS, *CsB1 = wts + 4 * MS;
  float* Cn0_2 = wts + 5 * MS, *Cn1_2 = wts + 6 * MS, *Cn2_2 = wts + 7 * MS;
  float* CsA2 = wts + 8 * MS, *CsB2 = wts + 9 * MS;
  float* cbA1 = wts + 10 * MS, *cbB1 = cbA1 + 128, *cbA2 = cbB1 + 128, *cbB2 = cbA2 + 128;

  size_t need_bytes = (4 * nh + 6 * (size_t)n + 10 * MS + 512) * sizeof(float);
  if (ws_size < need_bytes) {
    fprintf(stderr, "kernel_launch: ws too small (%zu < %zu)\n", ws_size, need_bytes);
    return;
  }

  // JAX keys: dk = split(key(42), 4)
  uint32_t dk[4][2];
#if JAX_PARTITIONABLE
  for (uint32_t i = 0; i < 4; ++i) tf2x32(0u, 42u, 0u, i, dk[i][0], dk[i][1]);
#else
  {
    uint32_t a8[8];
    for (uint32_t j = 0; j < 4; ++j) { uint32_t o0, o1; tf2x32(0u, 42u, j, j + 4u, o0, o1); a8[j] = o0; a8[j + 4] = o1; }
    for (int i = 0; i < 4; ++i) { dk[i][0] = a8[2 * i]; dk[i][1] = a8[2 * i + 1]; }
  }
#endif

  // combined weights
  WPack pk;
  const float* Wu1b = Wu1; const float* Wu2b = Wu2;
  auto U = [](const float* Wu, int t) { return Wu + (size_t)t * 32768; };
  auto L = [](const float* Wu, int t) { return Wu + (size_t)t * 32768 + 16384; };
  pk.d[0] = { Wn1 + 0 * MS, U(Wu1b, 0), nullptr, nullptr, Cn0_1 };
  pk.d[1] = { Wn1 + 1 * MS, U(Wu1b, 1), nullptr, nullptr, Cn1_1 };
  pk.d[2] = { Wn1 + 2 * MS, U(Wu1b, 2), nullptr, nullptr, Cn2_1 };
  pk.d[3] = { Ws1 + 0 * MS, L(Wu1b, 0), Ws1 + 2 * MS, L(Wu1b, 2), CsA1 };
  pk.d[4] = { Ws1 + 1 * MS, L(Wu1b, 1), nullptr, nullptr, CsB1 };
  pk.d[5] = { Wn2 + 0 * MS, U(Wu2b, 0), nullptr, nullptr, Cn0_2 };
  pk.d[6] = { Wn2 + 1 * MS, U(Wu2b, 1), nullptr, nullptr, Cn1_2 };
  pk.d[7] = { Wn2 + 2 * MS, U(Wu2b, 2), nullptr, nullptr, Cn2_2 };
  pk.d[8] = { Ws2 + 0 * MS, L(Wu2b, 0), Ws2 + 2 * MS, L(Wu2b, 2), CsA2 };
  pk.d[9] = { Ws2 + 1 * MS, L(Wu2b, 1), nullptr, nullptr, CsB2 };

  const int gdrop = (int)((nh + 255) / 256);
  const int gsc   = (int)(((size_t)E * 32 + 255) / 256);
  const int gcnt  = (E + 255) / 256;
  const int gmm   = (n + 63) / 64;

  hipMemsetAsync(cnt, 0, 3 * (size_t)n * sizeof(float), stream);
  k_wprec<<<40, 256, 0, stream>>>(pk);
  k_bias<<<1, 256, 0, stream>>>(bn1, bs1, bu1, Wu1, cbA1, cbB1);
  k_bias<<<1, 256, 0, stream>>>(bn2, bs2, bu2, Wu2, cbA2, cbB2);
  k_count<<<gcnt, 256, 0, stream>>>(ei0, cnt, E);
  k_count<<<gcnt, 256, 0, stream>>>(ei1, cnt + n, E);
  k_count<<<gcnt, 256, 0, stream>>>(ei2, cnt + 2 * n, E);
  k_inv<<<(3 * n + 255) / 256, 256, 0, stream>>>(cnt, inv, 3 * n);

  // input dropout+relu
  k_drop_relu<<<gdrop, 256, 0, stream>>>(xA, buf0, (int)nh, dk[0][0], dk[0][1]);
  k_drop_relu<<<gdrop, 256, 0, stream>>>(xB, buf1, (int)nh, dk[1][0], dk[1][1]);

  // ---- layer 1 ----
  hipMemsetAsync(buf2, 0, 2 * nh * sizeof(float), stream);      // aggr1, aggr2
  k_scatter<<<gsc, 256, 0, stream>>>(buf0, ei1, buf2, E);       // A->B msgs
  k_scatter<<<gsc, 256, 0, stream>>>(buf1, ei2, buf3, E);       // B->A msgs
  // oB1 = aggr1/deg @ Cn1 + hB @ CsB + cbB  -> buf2 (in-place)
  k_mm<2><<<gmm, 256, 0, stream>>>(buf2, inv + n, buf1, nullptr, nullptr, nullptr,
                                   Cn1_1, CsB1, nullptr, cbB1, buf2, n);
  hipMemsetAsync(buf1, 0, nh * sizeof(float), stream);          // aggr0
  k_scatter<<<gsc, 256, 0, stream>>>(buf0, ei0, buf1, E);       // A->A msgs
  // oA1 = aggr0/deg @ Cn0 + aggr2/deg @ Cn2 + hA @ CsA + cbA -> buf0 (in-place)
  k_mm<3><<<gmm, 256, 0, stream>>>(buf1, inv, buf3, inv + 2 * n, buf0, nullptr,
                                   Cn0_1, Cn2_1, CsA1, cbA1, buf0, n);

  // inter-layer dropout+relu (in place)
  k_drop_relu<<<gdrop, 256, 0, stream>>>(buf0, buf0, (int)nh, dk[2][0], dk[2][1]);  // h2A
  k_drop_relu<<<gdrop, 256, 0, stream>>>(buf2, buf2, (int)nh, dk[3][0], dk[3][1]);  // h2B

  // ---- layer 2 ----
  float* oA = (float*)d_out;
  float* oB = oA + nh;
  hipMemsetAsync(buf1, 0, nh * sizeof(float), stream);
  hipMemsetAsync(buf3, 0, nh * sizeof(float), stream);
  k_scatter<<<gsc, 256, 0, stream>>>(buf0, ei1, buf1, E);       // aggr1 (src h2A)
  k_scatter<<<gsc, 256, 0, stream>>>(buf2, ei2, buf3, E);       // aggr2 (src h2B)
  k_mm<2><<<gmm, 256, 0, stream>>>(buf1, inv + n, buf2, nullptr, nullptr, nullptr,
                                   Cn1_2, CsB2, nullptr, cbB2, oB, n);
  hipMemsetAsync(buf1, 0, nh * sizeof(float), stream);
  k_scatter<<<gsc, 256, 0, stream>>>(buf0, ei0, buf1, E);       // aggr0 (src h2A)
  k_mm<3><<<gmm, 256, 0, stream>>>(buf1, inv, buf3, inv + 2 * n, buf0, nullptr,
                                   Cn0_2, Cn2_2, CsA2, cbA2, oA, n);
}

// Round 3
// 2168.019 us; speedup vs baseline: 7.9384x; 7.9384x over previous
//
#include <hip/hip_runtime.h>
#include <cstdint>
#include <cstdio>

#define DIMF 128
#define JAX_PARTITIONABLE 1

// ---------------- JAX threefry2x32 (exact) ----------------
__host__ __device__ __forceinline__ void tf2x32(uint32_t k0, uint32_t k1,
                                                uint32_t x0, uint32_t x1,
                                                uint32_t& o0, uint32_t& o1) {
  uint32_t ks2 = k0 ^ k1 ^ 0x1BD11BDAu;
  x0 += k0; x1 += k1;
#define TFR(r) { x0 += x1; x1 = (x1 << (r)) | (x1 >> (32 - (r))); x1 ^= x0; }
  TFR(13) TFR(15) TFR(26) TFR(6)
  x0 += k1;  x1 += ks2 + 1u;
  TFR(17) TFR(29) TFR(16) TFR(24)
  x0 += ks2; x1 += k0 + 2u;
  TFR(13) TFR(15) TFR(26) TFR(6)
  x0 += k0;  x1 += k1 + 3u;
  TFR(17) TFR(29) TFR(16) TFR(24)
  x0 += k1;  x1 += ks2 + 4u;
  TFR(13) TFR(15) TFR(26) TFR(6)
  x0 += ks2; x1 += k0 + 5u;
#undef TFR
  o0 = x0; o1 = x1;
}

// ---------------- dropout(0.2) + relu, JAX-bit-exact mask ----------------
__global__ __launch_bounds__(256) void k_drop_relu(const float* __restrict__ in,
                                                   float* __restrict__ out,
                                                   int size, uint32_t k0, uint32_t k1) {
  int i = blockIdx.x * 256 + threadIdx.x;
  if (i >= size) return;
  uint32_t o0, o1, bits;
#if JAX_PARTITIONABLE
  tf2x32(k0, k1, 0u, (uint32_t)i, o0, o1);
  bits = o0 ^ o1;
#else
  uint32_t half = (uint32_t)(size / 2);
  uint32_t j = (uint32_t)i < half ? (uint32_t)i : (uint32_t)i - half;
  tf2x32(k0, k1, j, j + half, o0, o1);
  bits = ((uint32_t)i < half) ? o0 : o1;
#endif
  float u = __uint_as_float((bits >> 9) | 0x3f800000u) - 1.0f;
  float x = in[i];
  float y = (u < 0.8f) ? (x / 0.8f) : 0.0f;
  out[i] = fmaxf(y, 0.0f);
}

// ---------------- CSR build: count / scan / fill ----------------
__global__ __launch_bounds__(256) void k_count(const int* __restrict__ ei,
                                               int* __restrict__ cnt, int E) {
  int e = blockIdx.x * 256 + threadIdx.x;
  if (e < E) atomicAdd(cnt + ei[E + e], 1);
}

__global__ __launch_bounds__(256) void k_inv(const int* __restrict__ cnt,
                                             float* __restrict__ inv, int n) {
  int i = blockIdx.x * 256 + threadIdx.x;
  if (i < n) inv[i] = 1.0f / (float)max(cnt[i], 1);
}

// exclusive scan, 1024 elems/block; per-block totals to bsum
__global__ __launch_bounds__(256) void k_scanA(const int* __restrict__ cnt,
                                               int* __restrict__ off,
                                               int* __restrict__ bsum, int n3) {
  __shared__ int ts[256];
  int t = threadIdx.x;
  int base = blockIdx.x * 1024 + t * 4;
  int v[4];
#pragma unroll
  for (int i = 0; i < 4; ++i) v[i] = (base + i < n3) ? cnt[base + i] : 0;
  ts[t] = v[0] + v[1] + v[2] + v[3];
  __syncthreads();
  for (int ofs = 1; ofs < 256; ofs <<= 1) {
    int x = ts[t];
    int y = (t >= ofs) ? ts[t - ofs] : 0;
    __syncthreads();
    ts[t] = x + y;
    __syncthreads();
  }
  int run = (t == 0) ? 0 : ts[t - 1];
  if (t == 255) bsum[blockIdx.x] = ts[255];
#pragma unroll
  for (int i = 0; i < 4; ++i) {
    if (base + i < n3) off[base + i] = run;
    run += v[i];
  }
}

// scan the (<=1024) block sums in-place; write grand total to off[n3]
__global__ __launch_bounds__(256) void k_scanB(int* __restrict__ bsum, int nb,
                                               int* __restrict__ off, int n3) {
  __shared__ int ts[256];
  int t = threadIdx.x;
  int base = t * 4;
  int v[4];
#pragma unroll
  for (int i = 0; i < 4; ++i) v[i] = (base + i < nb) ? bsum[base + i] : 0;
  ts[t] = v[0] + v[1] + v[2] + v[3];
  __syncthreads();
  for (int ofs = 1; ofs < 256; ofs <<= 1) {
    int x = ts[t];
    int y = (t >= ofs) ? ts[t - ofs] : 0;
    __syncthreads();
    ts[t] = x + y;
    __syncthreads();
  }
  int run = (t == 0) ? 0 : ts[t - 1];
  if (t == 255) off[n3] = ts[255];
#pragma unroll
  for (int i = 0; i < 4; ++i) {
    if (base + i < nb) bsum[base + i] = run;
    run += v[i];
  }
}

__global__ __launch_bounds__(256) void k_scanC(int* __restrict__ off,
                                               const int* __restrict__ bsum,
                                               int* __restrict__ cur, int n3) {
  int i = blockIdx.x * 256 + threadIdx.x;
  if (i < n3) {
    int o = off[i] + bsum[i >> 10];
    off[i] = o;
    cur[i] = o;
  }
}

__global__ __launch_bounds__(256) void k_fill(const int* __restrict__ ei,
                                              int* __restrict__ cur,
                                              int* __restrict__ srcl, int E) {
  int e = blockIdx.x * 256 + threadIdx.x;
  if (e < E) {
    int pos = atomicAdd(cur + ei[E + e], 1);
    srcl[pos] = ei[e];
  }
}

// ---------------- CSR gather-mean: one wave per dst node ----------------
__global__ __launch_bounds__(256) void k_gather(const float* __restrict__ feat,
                                                const int* __restrict__ off,
                                                const int* __restrict__ srcl,
                                                const float* __restrict__ inv,
                                                float* __restrict__ out, int n) {
  int wid = (blockIdx.x * 256 + threadIdx.x) >> 6;
  int lane = threadIdx.x & 63;
  if (wid >= n) return;
  int b = off[wid], e = off[wid + 1];
  float2 a0 = make_float2(0.f, 0.f), a1 = make_float2(0.f, 0.f);
  int j = b;
  for (; j + 1 < e; j += 2) {
    int s0 = srcl[j], s1 = srcl[j + 1];
    float2 v0 = *(const float2*)(feat + (size_t)s0 * DIMF + lane * 2);
    float2 v1 = *(const float2*)(feat + (size_t)s1 * DIMF + lane * 2);
    a0.x += v0.x; a0.y += v0.y;
    a1.x += v1.x; a1.y += v1.y;
  }
  if (j < e) {
    int s = srcl[j];
    float2 v = *(const float2*)(feat + (size_t)s * DIMF + lane * 2);
    a0.x += v.x; a0.y += v.y;
  }
  float sc = inv[wid];
  float2 r = make_float2((a0.x + a1.x) * sc, (a0.y + a1.y) * sc);
  *(float2*)(out + (size_t)wid * DIMF + lane * 2) = r;
}

// ---------------- combined-weight precompute: C = A0@B0 (+ A1@B1) ----------------
struct WDesc { const float* A0; const float* B0; const float* A1; const float* B1; float* C; };
struct WPack { WDesc d[10]; };

__global__ __launch_bounds__(256) void k_wprec(WPack p) {
  const WDesc d = p.d[blockIdx.x >> 2];
  const int rt = blockIdx.x & 3;
  __shared__ float A_s[32 * 128];
  const int t = threadIdx.x;
  const int c = t & 127, rh = t >> 7;
  float acc[16];
#pragma unroll
  for (int i = 0; i < 16; ++i) acc[i] = 0.f;
  for (int pass = 0; pass < 2; ++pass) {
    const float* A = pass ? d.A1 : d.A0;
    const float* B = pass ? d.B1 : d.B0;
    if (!A) break;
    __syncthreads();
#pragma unroll
    for (int j = 0; j < 4; ++j) {
      int f = t + 256 * j;
      *(float4*)(A_s + 4 * f) = *(const float4*)(A + (size_t)rt * 32 * 128 + 4 * f);
    }
    __syncthreads();
    for (int k = 0; k < 128; ++k) {
      float b = B[(size_t)k * 128 + c];
#pragma unroll
      for (int i = 0; i < 16; ++i)
        acc[i] += A_s[(rh + 2 * i) * 128 + k] * b;
    }
  }
#pragma unroll
  for (int i = 0; i < 16; ++i)
    d.C[(size_t)(rt * 32 + rh + 2 * i) * 128 + c] = acc[i];
}

// ---------------- combined bias ----------------
__global__ __launch_bounds__(256) void k_bias(const float* __restrict__ bn,
                                              const float* __restrict__ bs,
                                              const float* __restrict__ bu,
                                              const float* __restrict__ Wu,
                                              float* __restrict__ cbA, float* __restrict__ cbB) {
  int t = threadIdx.x;
  int h = t & 127;
  if (t < 128) {
    float acc = bu[0 * 128 + h] + bu[2 * 128 + h];
    for (int j = 0; j < 128; ++j) {
      acc += bn[0 * 128 + j] * Wu[(size_t)0 * 32768 + (size_t)j * 128 + h];
      acc += bs[0 * 128 + j] * Wu[(size_t)0 * 32768 + 16384 + (size_t)j * 128 + h];
      acc += bn[2 * 128 + j] * Wu[(size_t)2 * 32768 + (size_t)j * 128 + h];
      acc += bs[2 * 128 + j] * Wu[(size_t)2 * 32768 + 16384 + (size_t)j * 128 + h];
    }
    cbA[h] = acc;
  } else {
    float acc = bu[128 + h];
    for (int j = 0; j < 128; ++j) {
      acc += bn[128 + j] * Wu[(size_t)1 * 32768 + (size_t)j * 128 + h];
      acc += bs[128 + j] * Wu[(size_t)1 * 32768 + 16384 + (size_t)j * 128 + h];
    }
    cbB[h] = acc;
  }
}

// ---------------- fused multi-term matmul (in-place safe per 64-row block) ----------------
template <int NT>
__global__ __launch_bounds__(256) void k_mm(
    const float* __restrict__ s0, const float* __restrict__ s1, const float* __restrict__ s2,
    const float* __restrict__ w0, const float* __restrict__ w1, const float* __restrict__ w2,
    const float* __restrict__ bias,
    float* __restrict__ out, int nrows) {
  __shared__ float a_s[64 * 36];
  __shared__ float w_s[32 * 128];
  const int t = threadIdx.x;
  const int r0 = blockIdx.x * 64;
  const int cg = t & 7;
  const int rp = t >> 3;
  float4 acc[2][4];
#pragma unroll
  for (int q = 0; q < 4; ++q) {
    float4 b = *(const float4*)(bias + cg * 4 + 32 * q);
    acc[0][q] = b; acc[1][q] = b;
  }
#pragma unroll
  for (int term = 0; term < NT; ++term) {
    const float* src = term == 0 ? s0 : (term == 1 ? s1 : s2);
    const float* Wt  = term == 0 ? w0 : (term == 1 ? w1 : w2);
    for (int kc = 0; kc < 4; ++kc) {
      __syncthreads();
      {
        int fq = t & 7, row = t >> 3;
#pragma unroll
        for (int h = 0; h < 2; ++h) {
          int r = row + 32 * h;
          int gr = r0 + r;
          float4 v = make_float4(0.f, 0.f, 0.f, 0.f);
          if (gr < nrows) v = *(const float4*)(src + (size_t)gr * 128 + kc * 32 + fq * 4);
          *(float4*)(a_s + r * 36 + fq * 4) = v;
        }
      }
      {
#pragma unroll
        for (int j = 0; j < 4; ++j) {
          int f = t + 256 * j;
          int kr = f >> 5, c4 = (f & 31) << 2;
          *(float4*)(w_s + kr * 128 + c4) = *(const float4*)(Wt + (size_t)(kc * 32 + kr) * 128 + c4);
        }
      }
      __syncthreads();
#pragma unroll 8
      for (int k = 0; k < 32; ++k) {
        float a0 = a_s[rp * 36 + k];
        float a1 = a_s[(rp + 32) * 36 + k];
#pragma unroll
        for (int q = 0; q < 4; ++q) {
          float4 w = *(const float4*)(w_s + k * 128 + cg * 4 + 32 * q);
          acc[0][q].x += a0 * w.x; acc[0][q].y += a0 * w.y;
          acc[0][q].z += a0 * w.z; acc[0][q].w += a0 * w.w;
          acc[1][q].x += a1 * w.x; acc[1][q].y += a1 * w.y;
          acc[1][q].z += a1 * w.z; acc[1][q].w += a1 * w.w;
        }
      }
    }
  }
#pragma unroll
  for (int h = 0; h < 2; ++h) {
    int gr = r0 + rp + 32 * h;
    if (gr < nrows) {
#pragma unroll
      for (int q = 0; q < 4; ++q)
        *(float4*)(out + (size_t)gr * 128 + cg * 4 + 32 * q) = acc[h][q];
    }
  }
}

// ---------------- host driver ----------------
extern "C" void kernel_launch(void* const* d_in, const int* in_sizes, int n_in,
                              void* d_out, int out_size, void* d_ws, size_t ws_size,
                              hipStream_t stream) {
  const float* xA  = (const float*)d_in[0];
  const float* xB  = (const float*)d_in[1];
  const int*   ei0 = (const int*)d_in[2];
  const int*   ei1 = (const int*)d_in[3];
  const int*   ei2 = (const int*)d_in[4];
  const float* Wn1 = (const float*)d_in[5];
  const float* Ws1 = (const float*)d_in[6];
  const float* Wu1 = (const float*)d_in[7];
  const float* Wn2 = (const float*)d_in[8];
  const float* Ws2 = (const float*)d_in[9];
  const float* Wu2 = (const float*)d_in[10];
  const float* bn1 = (const float*)d_in[11];
  const float* bs1 = (const float*)d_in[12];
  const float* bu1 = (const float*)d_in[13];
  const float* bn2 = (const float*)d_in[14];
  const float* bs2 = (const float*)d_in[15];
  const float* bu2 = (const float*)d_in[16];

  const int n  = in_sizes[0] / DIMF;        // 100000
  const int E  = in_sizes[2] / 2;           // 1600000
  const int n3 = 3 * n;
  const size_t nh = (size_t)n * DIMF;
  const size_t MS = 128 * 128;

  float* ws   = (float*)d_ws;
  float* buf0 = ws;                         // hA / oA1 / h2A
  float* buf1 = buf0 + nh;                  // hB / oB1 / h2B
  float* buf2 = buf1 + nh;                  // gathered aggr (ei2)
  float* buf3 = buf2 + nh;                  // gathered aggr (ei1 / ei0)
  float* wts  = buf3 + nh;
  float* Cn0_1 = wts + 0 * MS, *Cn1_1 = wts + 1 * MS, *Cn2_1 = wts + 2 * MS;
  float* CsA1 = wts + 3 * MS, *CsB1 = wts + 4 * MS;
  float* Cn0_2 = wts + 5 * MS, *Cn1_2 = wts + 6 * MS, *Cn2_2 = wts + 7 * MS;
  float* CsA2 = wts + 8 * MS, *CsB2 = wts + 9 * MS;
  float* cbA1 = wts + 10 * MS, *cbB1 = cbA1 + 128, *cbA2 = cbB1 + 128, *cbB2 = cbA2 + 128;
  float* inv  = cbB2 + 128;                 // [3n]
  int* cnt  = (int*)(inv + n3);             // [3n]
  int* off  = cnt + n3;                     // [3n+1]
  int* cur  = off + n3 + 1;                 // [3n]
  int* bsum = cur + n3;                     // [1024]
  int* srcl = bsum + 1024;                  // [3E]

  size_t need_bytes = (4 * nh + 10 * MS + 512 + (size_t)n3) * sizeof(float)
                    + ((size_t)3 * n3 + 1 + 1024 + (size_t)3 * E) * sizeof(int);
  if (ws_size < need_bytes) {
    fprintf(stderr, "kernel_launch: ws too small (%zu < %zu)\n", ws_size, need_bytes);
    return;
  }

  uint32_t dk[4][2];
#if JAX_PARTITIONABLE
  for (uint32_t i = 0; i < 4; ++i) tf2x32(0u, 42u, 0u, i, dk[i][0], dk[i][1]);
#else
  {
    uint32_t a8[8];
    for (uint32_t j = 0; j < 4; ++j) { uint32_t o0, o1; tf2x32(0u, 42u, j, j + 4u, o0, o1); a8[j] = o0; a8[j + 4] = o1; }
    for (int i = 0; i < 4; ++i) { dk[i][0] = a8[2 * i]; dk[i][1] = a8[2 * i + 1]; }
  }
#endif

  WPack pk;
  auto U = [](const float* Wu, int t) { return Wu + (size_t)t * 32768; };
  auto L = [](const float* Wu, int t) { return Wu + (size_t)t * 32768 + 16384; };
  pk.d[0] = { Wn1 + 0 * MS, U(Wu1, 0), nullptr, nullptr, Cn0_1 };
  pk.d[1] = { Wn1 + 1 * MS, U(Wu1, 1), nullptr, nullptr, Cn1_1 };
  pk.d[2] = { Wn1 + 2 * MS, U(Wu1, 2), nullptr, nullptr, Cn2_1 };
  pk.d[3] = { Ws1 + 0 * MS, L(Wu1, 0), Ws1 + 2 * MS, L(Wu1, 2), CsA1 };
  pk.d[4] = { Ws1 + 1 * MS, L(Wu1, 1), nullptr, nullptr, CsB1 };
  pk.d[5] = { Wn2 + 0 * MS, U(Wu2, 0), nullptr, nullptr, Cn0_2 };
  pk.d[6] = { Wn2 + 1 * MS, U(Wu2, 1), nullptr, nullptr, Cn1_2 };
  pk.d[7] = { Wn2 + 2 * MS, U(Wu2, 2), nullptr, nullptr, Cn2_2 };
  pk.d[8] = { Ws2 + 0 * MS, L(Wu2, 0), Ws2 + 2 * MS, L(Wu2, 2), CsA2 };
  pk.d[9] = { Ws2 + 1 * MS, L(Wu2, 1), nullptr, nullptr, CsB2 };

  const int gdrop = (int)((nh + 255) / 256);
  const int gE    = (E + 255) / 256;
  const int gmm   = (n + 63) / 64;
  const int gga   = (n * 64 + 255) / 256;   // one wave per dst
  const int nbA   = (n3 + 1023) / 1024;

  // ---- CSR build (ei fixed inputs; rebuilt every call for determinism) ----
  hipMemsetAsync(cnt, 0, (size_t)n3 * sizeof(int), stream);
  k_count<<<gE, 256, 0, stream>>>(ei0, cnt, E);
  k_count<<<gE, 256, 0, stream>>>(ei1, cnt + n, E);
  k_count<<<gE, 256, 0, stream>>>(ei2, cnt + 2 * n, E);
  k_inv<<<(n3 + 255) / 256, 256, 0, stream>>>(cnt, inv, n3);
  k_scanA<<<nbA, 256, 0, stream>>>(cnt, off, bsum, n3);
  k_scanB<<<1, 256, 0, stream>>>(bsum, nbA, off, n3);
  k_scanC<<<(n3 + 255) / 256, 256, 0, stream>>>(off, bsum, cur, n3);
  k_fill<<<gE, 256, 0, stream>>>(ei0, cur, srcl, E);
  k_fill<<<gE, 256, 0, stream>>>(ei1, cur + n, srcl, E);
  k_fill<<<gE, 256, 0, stream>>>(ei2, cur + 2 * n, srcl, E);

  // ---- weights / biases ----
  k_wprec<<<40, 256, 0, stream>>>(pk);
  k_bias<<<1, 256, 0, stream>>>(bn1, bs1, bu1, Wu1, cbA1, cbB1);
  k_bias<<<1, 256, 0, stream>>>(bn2, bs2, bu2, Wu2, cbA2, cbB2);

  // ---- input dropout+relu ----
  k_drop_relu<<<gdrop, 256, 0, stream>>>(xA, buf0, (int)nh, dk[0][0], dk[0][1]);
  k_drop_relu<<<gdrop, 256, 0, stream>>>(xB, buf1, (int)nh, dk[1][0], dk[1][1]);

  // ---- layer 1 ----
  k_gather<<<gga, 256, 0, stream>>>(buf1, off + 2 * n, srcl, inv + 2 * n, buf2, n); // B->A (ei2)
  k_gather<<<gga, 256, 0, stream>>>(buf0, off + n, srcl, inv + n, buf3, n);         // A->B (ei1)
  k_mm<2><<<gmm, 256, 0, stream>>>(buf3, buf1, nullptr,
                                   Cn1_1, CsB1, nullptr, cbB1, buf1, n);            // oB1 (in place)
  k_gather<<<gga, 256, 0, stream>>>(buf0, off, srcl, inv, buf3, n);                 // A->A (ei0)
  k_mm<3><<<gmm, 256, 0, stream>>>(buf3, buf2, buf0,
                                   Cn0_1, Cn2_1, CsA1, cbA1, buf0, n);              // oA1 (in place)

  // ---- inter-layer dropout+relu (in place) ----
  k_drop_relu<<<gdrop, 256, 0, stream>>>(buf0, buf0, (int)nh, dk[2][0], dk[2][1]);  // h2A
  k_drop_relu<<<gdrop, 256, 0, stream>>>(buf1, buf1, (int)nh, dk[3][0], dk[3][1]);  // h2B

  // ---- layer 2 ----
  float* oA = (float*)d_out;
  float* oB = oA + nh;
  k_gather<<<gga, 256, 0, stream>>>(buf1, off + 2 * n, srcl, inv + 2 * n, buf2, n); // B->A
  k_gather<<<gga, 256, 0, stream>>>(buf0, off + n, srcl, inv + n, buf3, n);         // A->B
  k_mm<2><<<gmm, 256, 0, stream>>>(buf3, buf1, nullptr,
                                   Cn1_2, CsB2, nullptr, cbB2, oB, n);              // oB2
  k_gather<<<gga, 256, 0, stream>>>(buf0, off, srcl, inv, buf3, n);                 // A->A
  k_mm<3><<<gmm, 256, 0, stream>>>(buf3, buf2, buf0,
                                   Cn0_2, Cn2_2, CsA2, cbA2, oA, n);                // oA2
}

// Round 4
// 1702.640 us; speedup vs baseline: 10.1082x; 1.2733x over previous
//
#include <hip/hip_runtime.h>
#include <cstdint>
#include <cstdio>

#define DIMF 128

typedef __attribute__((ext_vector_type(8))) short short8v;
typedef __attribute__((ext_vector_type(4))) float f32x4;

// ---------------- JAX threefry2x32 (exact) ----------------
__host__ __device__ __forceinline__ void tf2x32(uint32_t k0, uint32_t k1,
                                                uint32_t x0, uint32_t x1,
                                                uint32_t& o0, uint32_t& o1) {
  uint32_t ks2 = k0 ^ k1 ^ 0x1BD11BDAu;
  x0 += k0; x1 += k1;
#define TFR(r) { x0 += x1; x1 = (x1 << (r)) | (x1 >> (32 - (r))); x1 ^= x0; }
  TFR(13) TFR(15) TFR(26) TFR(6)
  x0 += k1;  x1 += ks2 + 1u;
  TFR(17) TFR(29) TFR(16) TFR(24)
  x0 += ks2; x1 += k0 + 2u;
  TFR(13) TFR(15) TFR(26) TFR(6)
  x0 += k0;  x1 += k1 + 3u;
  TFR(17) TFR(29) TFR(16) TFR(24)
  x0 += k1;  x1 += ks2 + 4u;
  TFR(13) TFR(15) TFR(26) TFR(6)
  x0 += ks2; x1 += k0 + 5u;
#undef TFR
  o0 = x0; o1 = x1;
}

__device__ __forceinline__ short f2bf_rne(float x) {
  uint32_t u = __float_as_uint(x);
  uint32_t r = (u + 0x7FFFu + ((u >> 16) & 1u)) >> 16;
  return (short)r;
}
__device__ __forceinline__ float bfhi_f(short h) {
  return __uint_as_float(((uint32_t)(uint16_t)h) << 16);
}

// ---------------- input dropout(0.2)+relu -> hi/lo bf16 rows [128hi|128lo] ----------------
__global__ __launch_bounds__(256) void k_drop_in(const float* __restrict__ in,
                                                 short* __restrict__ out,
                                                 int npair, uint32_t k0, uint32_t k1) {
  int p = blockIdx.x * 256 + threadIdx.x;
  if (p >= npair) return;
  int row = p >> 6, c2 = (p & 63) * 2;
  float2 x = *(const float2*)(in + (size_t)row * 128 + c2);
  uint32_t idx = (uint32_t)(row * 128 + c2);
  float v[2] = {x.x, x.y};
  short hi[2], lo[2];
#pragma unroll
  for (int q = 0; q < 2; ++q) {
    uint32_t o0, o1;
    tf2x32(k0, k1, 0u, idx + q, o0, o1);
    uint32_t bits = o0 ^ o1;
    float u = __uint_as_float((bits >> 9) | 0x3f800000u) - 1.0f;
    float y = (u < 0.8f) ? (v[q] / 0.8f) : 0.0f;
    y = fmaxf(y, 0.0f);
    hi[q] = f2bf_rne(y);
    lo[q] = f2bf_rne(y - bfhi_f(hi[q]));
  }
  uint32_t hp = (uint32_t)(uint16_t)hi[0] | ((uint32_t)(uint16_t)hi[1] << 16);
  uint32_t lp = (uint32_t)(uint16_t)lo[0] | ((uint32_t)(uint16_t)lo[1] << 16);
  *(uint32_t*)(out + (size_t)row * 256 + c2) = hp;
  *(uint32_t*)(out + (size_t)row * 256 + 128 + c2) = lp;
}

// ---------------- CSR build ----------------
__global__ __launch_bounds__(256) void k_count(const int* __restrict__ ei,
                                               int* __restrict__ cnt, int E) {
  int e = blockIdx.x * 256 + threadIdx.x;
  if (e < E) atomicAdd(cnt + ei[E + e], 1);
}

__global__ __launch_bounds__(256) void k_scanA(const int* __restrict__ cnt,
                                               int* __restrict__ off,
                                               int* __restrict__ bsum, int n3) {
  __shared__ int ts[256];
  int t = threadIdx.x;
  int base = blockIdx.x * 1024 + t * 4;
  int v[4];
#pragma unroll
  for (int i = 0; i < 4; ++i) v[i] = (base + i < n3) ? cnt[base + i] : 0;
  ts[t] = v[0] + v[1] + v[2] + v[3];
  __syncthreads();
  for (int ofs = 1; ofs < 256; ofs <<= 1) {
    int x = ts[t];
    int y = (t >= ofs) ? ts[t - ofs] : 0;
    __syncthreads();
    ts[t] = x + y;
    __syncthreads();
  }
  int run = (t == 0) ? 0 : ts[t - 1];
  if (t == 255) bsum[blockIdx.x] = ts[255];
#pragma unroll
  for (int i = 0; i < 4; ++i) {
    if (base + i < n3) off[base + i] = run;
    run += v[i];
  }
}

__global__ __launch_bounds__(256) void k_scanB(int* __restrict__ bsum, int nb,
                                               int* __restrict__ off, int n3) {
  __shared__ int ts[256];
  int t = threadIdx.x;
  int base = t * 4;
  int v[4];
#pragma unroll
  for (int i = 0; i < 4; ++i) v[i] = (base + i < nb) ? bsum[base + i] : 0;
  ts[t] = v[0] + v[1] + v[2] + v[3];
  __syncthreads();
  for (int ofs = 1; ofs < 256; ofs <<= 1) {
    int x = ts[t];
    int y = (t >= ofs) ? ts[t - ofs] : 0;
    __syncthreads();
    ts[t] = x + y;
    __syncthreads();
  }
  int run = (t == 0) ? 0 : ts[t - 1];
  if (t == 255) off[n3] = ts[255];
#pragma unroll
  for (int i = 0; i < 4; ++i) {
    if (base + i < nb) bsum[base + i] = run;
    run += v[i];
  }
}

__global__ __launch_bounds__(256) void k_scanC(int* __restrict__ off,
                                               const int* __restrict__ bsum,
                                               int* __restrict__ cur, int n3) {
  int i = blockIdx.x * 256 + threadIdx.x;
  if (i < n3) {
    int o = off[i] + bsum[i >> 10];
    off[i] = o;
    cur[i] = o;
  }
}

__global__ __launch_bounds__(256) void k_fill(const int* __restrict__ ei,
                                              int* __restrict__ cur,
                                              int* __restrict__ srcl, int E) {
  int e = blockIdx.x * 256 + threadIdx.x;
  if (e < E) {
    int pos = atomicAdd(cur + ei[E + e], 1);
    srcl[pos] = ei[e];
  }
}

// ---------------- CSR gather-mean over hi/lo rows -> hi/lo out ----------------
__global__ __launch_bounds__(256) void k_gather(const short* __restrict__ feat,
                                                const int* __restrict__ off,
                                                const int* __restrict__ srcl,
                                                short* __restrict__ out, int n) {
  int wid = (blockIdx.x * 256 + threadIdx.x) >> 6;
  int lane = threadIdx.x & 63;
  if (wid >= n) return;
  int b = off[wid], e = off[wid + 1];
  const int c0 = lane * 2;
  float a0 = 0.f, a1 = 0.f, b0 = 0.f, b1 = 0.f;
  int j = b;
  for (; j + 1 < e; j += 2) {
    const short* p0 = feat + (size_t)srcl[j] * 256 + c0;
    const short* p1 = feat + (size_t)srcl[j + 1] * 256 + c0;
    uint32_t h0 = *(const uint32_t*)p0, l0 = *(const uint32_t*)(p0 + 128);
    uint32_t h1 = *(const uint32_t*)p1, l1 = *(const uint32_t*)(p1 + 128);
    a0 += __uint_as_float(h0 << 16) + __uint_as_float(l0 << 16);
    a1 += __uint_as_float(h0 & 0xFFFF0000u) + __uint_as_float(l0 & 0xFFFF0000u);
    b0 += __uint_as_float(h1 << 16) + __uint_as_float(l1 << 16);
    b1 += __uint_as_float(h1 & 0xFFFF0000u) + __uint_as_float(l1 & 0xFFFF0000u);
  }
  if (j < e) {
    const short* p0 = feat + (size_t)srcl[j] * 256 + c0;
    uint32_t h0 = *(const uint32_t*)p0, l0 = *(const uint32_t*)(p0 + 128);
    a0 += __uint_as_float(h0 << 16) + __uint_as_float(l0 << 16);
    a1 += __uint_as_float(h0 & 0xFFFF0000u) + __uint_as_float(l0 & 0xFFFF0000u);
  }
  float sc = 1.0f / (float)max(e - b, 1);
  float v0 = (a0 + b0) * sc, v1 = (a1 + b1) * sc;
  short h0 = f2bf_rne(v0), h1 = f2bf_rne(v1);
  short l0s = f2bf_rne(v0 - bfhi_f(h0)), l1s = f2bf_rne(v1 - bfhi_f(h1));
  uint32_t hp = (uint32_t)(uint16_t)h0 | ((uint32_t)(uint16_t)h1 << 16);
  uint32_t lp = (uint32_t)(uint16_t)l0s | ((uint32_t)(uint16_t)l1s << 16);
  *(uint32_t*)(out + (size_t)wid * 256 + c0) = hp;
  *(uint32_t*)(out + (size_t)wid * 256 + 128 + c0) = lp;
}

// ---------------- combined-weight precompute: C=A0@B0(+A1@B1) -> transposed hi/lo bf16 ----------------
struct WDesc { const float* A0; const float* B0; const float* A1; const float* B1; short* Ch; short* Cl; };
struct WPack { WDesc d[10]; };

__global__ __launch_bounds__(256) void k_wprec(WPack p) {
  const WDesc d = p.d[blockIdx.x >> 2];
  const int rt = blockIdx.x & 3;
  __shared__ float A_s[32 * 128];
  const int t = threadIdx.x;
  const int c = t & 127, rh = t >> 7;
  float acc[16];
#pragma unroll
  for (int i = 0; i < 16; ++i) acc[i] = 0.f;
  for (int pass = 0; pass < 2; ++pass) {
    const float* A = pass ? d.A1 : d.A0;
    const float* B = pass ? d.B1 : d.B0;
    if (!A) break;
    __syncthreads();
#pragma unroll
    for (int j = 0; j < 4; ++j) {
      int f = t + 256 * j;
      *(float4*)(A_s + 4 * f) = *(const float4*)(A + (size_t)rt * 32 * 128 + 4 * f);
    }
    __syncthreads();
    for (int k = 0; k < 128; ++k) {
      float b = B[(size_t)k * 128 + c];
#pragma unroll
      for (int i = 0; i < 16; ++i)
        acc[i] += A_s[(rh + 2 * i) * 128 + k] * b;
    }
  }
  // write transposed: Wt[n=c][k], split hi/lo
#pragma unroll
  for (int i = 0; i < 16; ++i) {
    int k = rt * 32 + rh + 2 * i;
    float v = acc[i];
    short hi = f2bf_rne(v);
    short lo = f2bf_rne(v - bfhi_f(hi));
    d.Ch[(size_t)c * 128 + k] = hi;
    d.Cl[(size_t)c * 128 + k] = lo;
  }
}

// ---------------- combined bias ----------------
__global__ __launch_bounds__(256) void k_bias(const float* __restrict__ bn,
                                              const float* __restrict__ bs,
                                              const float* __restrict__ bu,
                                              const float* __restrict__ Wu,
                                              float* __restrict__ cbA, float* __restrict__ cbB) {
  int t = threadIdx.x;
  int h = t & 127;
  if (t < 128) {
    float acc = bu[0 * 128 + h] + bu[2 * 128 + h];
    for (int j = 0; j < 128; ++j) {
      acc += bn[0 * 128 + j] * Wu[(size_t)0 * 32768 + (size_t)j * 128 + h];
      acc += bs[0 * 128 + j] * Wu[(size_t)0 * 32768 + 16384 + (size_t)j * 128 + h];
      acc += bn[2 * 128 + j] * Wu[(size_t)2 * 32768 + (size_t)j * 128 + h];
      acc += bs[2 * 128 + j] * Wu[(size_t)2 * 32768 + 16384 + (size_t)j * 128 + h];
    }
    cbA[h] = acc;
  } else {
    float acc = bu[128 + h];
    for (int j = 0; j < 128; ++j) {
      acc += bn[128 + j] * Wu[(size_t)1 * 32768 + (size_t)j * 128 + h];
      acc += bs[128 + j] * Wu[(size_t)1 * 32768 + 16384 + (size_t)j * 128 + h];
    }
    cbB[h] = acc;
  }
}

// ---------------- split-bf16 MFMA multi-term matmul ----------------
// out = sum_t s_t @ C_t + bias; s_t are hi/lo bf16 rows [128hi|128lo].
// MODE 0: f32 out. MODE 1: dropout+relu -> hi/lo bf16 out (in-place safe per 128-row block).
// MFMA layouts: C/D col=lane&15,row=(lane>>4)*4+reg (m89); A row=lane&15,k=(lane>>4)*8+j;
//               B col=lane&15,k=(lane>>4)*8+j.
template <int NT, int MODE>
__global__ __launch_bounds__(256, 2) void k_mmx(
    const short* __restrict__ s0, const short* __restrict__ s1, const short* __restrict__ s2,
    const short* __restrict__ w0h, const short* __restrict__ w0l,
    const short* __restrict__ w1h, const short* __restrict__ w1l,
    const short* __restrict__ w2h, const short* __restrict__ w2l,
    const float* __restrict__ bias, void* __restrict__ outv, int n,
    uint32_t k0, uint32_t k1) {
  __shared__ short A_s[128 * 72];   // [row][32hi|32lo|8pad], 144B stride
  __shared__ short W_s[128 * 72];   // [n][32hi|32lo|8pad] (Wt is n-major)
  const int t = threadIdx.x;
  const int r0 = blockIdx.x * 128;
  const int lane = t & 63;
  const int w = t >> 6;
  const int wr = w >> 1, wc = w & 1;
  const int lr = lane & 15, lg = lane >> 4;
  const int sr = t >> 1, sh = t & 1;

  f32x4 acc[4][4];
#pragma unroll
  for (int nf = 0; nf < 4; ++nf) {
    float bv = bias[wc * 64 + nf * 16 + lr];
#pragma unroll
    for (int mf = 0; mf < 4; ++mf) acc[mf][nf] = {bv, bv, bv, bv};
  }

  for (int term = 0; term < NT; ++term) {
    const short* src = term == 0 ? s0 : (term == 1 ? s1 : s2);
    const short* wh  = term == 0 ? w0h : (term == 1 ? w1h : w2h);
    const short* wl  = term == 0 ? w0l : (term == 1 ? w1l : w2l);
    const short* wsrc = sh ? wl : wh;
    for (int ks = 0; ks < 4; ++ks) {
      __syncthreads();
      {
        const uint4* ga = (const uint4*)(src + (size_t)(r0 + sr) * 256 + sh * 128 + ks * 32);
        const uint4* gw = (const uint4*)(wsrc + sr * 128 + ks * 32);
        uint4 a0 = ga[0], a1 = ga[1], a2 = ga[2], a3 = ga[3];
        uint4 b0 = gw[0], b1 = gw[1], b2 = gw[2], b3 = gw[3];
        uint4* la = (uint4*)(A_s + sr * 72 + sh * 32);
        uint4* lw = (uint4*)(W_s + sr * 72 + sh * 32);
        la[0] = a0; la[1] = a1; la[2] = a2; la[3] = a3;
        lw[0] = b0; lw[1] = b1; lw[2] = b2; lw[3] = b3;
      }
      __syncthreads();
      short8v whi[4], wlo[4];
#pragma unroll
      for (int nf = 0; nf < 4; ++nf) {
        int nc = wc * 64 + nf * 16 + lr;
        whi[nf] = *(const short8v*)(W_s + nc * 72 + lg * 8);
        wlo[nf] = *(const short8v*)(W_s + nc * 72 + 32 + lg * 8);
      }
#pragma unroll
      for (int mf = 0; mf < 4; ++mf) {
        int ar = wr * 64 + mf * 16 + lr;
        short8v ah = *(const short8v*)(A_s + ar * 72 + lg * 8);
        short8v al = *(const short8v*)(A_s + ar * 72 + 32 + lg * 8);
#pragma unroll
        for (int nf = 0; nf < 4; ++nf) {
          acc[mf][nf] = __builtin_amdgcn_mfma_f32_16x16x32_bf16(ah, whi[nf], acc[mf][nf], 0, 0, 0);
          acc[mf][nf] = __builtin_amdgcn_mfma_f32_16x16x32_bf16(ah, wlo[nf], acc[mf][nf], 0, 0, 0);
          acc[mf][nf] = __builtin_amdgcn_mfma_f32_16x16x32_bf16(al, whi[nf], acc[mf][nf], 0, 0, 0);
        }
      }
    }
  }

#pragma unroll
  for (int mf = 0; mf < 4; ++mf) {
#pragma unroll
    for (int r = 0; r < 4; ++r) {
      int g = r0 + wr * 64 + mf * 16 + lg * 4 + r;
      if (g >= n) continue;
#pragma unroll
      for (int nf = 0; nf < 4; ++nf) {
        int col = wc * 64 + nf * 16 + lr;
        float v = acc[mf][nf][r];
        if constexpr (MODE == 1) {
          uint32_t o0, o1;
          tf2x32(k0, k1, 0u, (uint32_t)(g * 128 + col), o0, o1);
          uint32_t bits = o0 ^ o1;
          float u = __uint_as_float((bits >> 9) | 0x3f800000u) - 1.0f;
          v = (u < 0.8f) ? (v / 0.8f) : 0.0f;
          v = fmaxf(v, 0.0f);
          short hi = f2bf_rne(v);
          short lo = f2bf_rne(v - bfhi_f(hi));
          short* o = (short*)outv + (size_t)g * 256 + col;
          o[0] = hi;
          o[128] = lo;
        } else {
          ((float*)outv)[(size_t)g * 128 + col] = v;
        }
      }
    }
  }
}

// ---------------- host driver ----------------
extern "C" void kernel_launch(void* const* d_in, const int* in_sizes, int n_in,
                              void* d_out, int out_size, void* d_ws, size_t ws_size,
                              hipStream_t stream) {
  const float* xA  = (const float*)d_in[0];
  const float* xB  = (const float*)d_in[1];
  const int*   ei0 = (const int*)d_in[2];
  const int*   ei1 = (const int*)d_in[3];
  const int*   ei2 = (const int*)d_in[4];
  const float* Wn1 = (const float*)d_in[5];
  const float* Ws1 = (const float*)d_in[6];
  const float* Wu1 = (const float*)d_in[7];
  const float* Wn2 = (const float*)d_in[8];
  const float* Ws2 = (const float*)d_in[9];
  const float* Wu2 = (const float*)d_in[10];
  const float* bn1 = (const float*)d_in[11];
  const float* bs1 = (const float*)d_in[12];
  const float* bu1 = (const float*)d_in[13];
  const float* bn2 = (const float*)d_in[14];
  const float* bs2 = (const float*)d_in[15];
  const float* bu2 = (const float*)d_in[16];

  const int n  = in_sizes[0] / DIMF;        // 100000
  const int E  = in_sizes[2] / 2;           // 1600000
  const int n3 = 3 * n;
  const size_t nh = (size_t)n * DIMF;

  float* ws = (float*)d_ws;
  // hi/lo feature buffers occupy nh floats' worth of bytes each (n x 512B)
  short* buf_hA = (short*)(ws);             // hA_hl -> h2A_hl (in place)
  short* buf_hB = (short*)(ws + nh);        // hB_hl -> h2B_hl (in place)
  short* g1     = (short*)(ws + 2 * nh);    // gather scratch
  short* g2     = (short*)(ws + 3 * nh);    // gather scratch
  short* wtsS   = (short*)(ws + 4 * nh);    // 10 x (16384 hi + 16384 lo) shorts
  float* biasF  = (float*)(wtsS + 10 * 32768);
  float* cbA1 = biasF, *cbB1 = biasF + 128, *cbA2 = biasF + 256, *cbB2 = biasF + 384;
  int* cnt  = (int*)(biasF + 512);          // [3n]
  int* off  = cnt + n3;                     // [3n+1]
  int* cur  = off + n3 + 1;                 // [3n]
  int* bsum = cur + n3;                     // [1024]
  int* srcl = bsum + 1024;                  // [3E]

  size_t need_bytes = (4 * nh + 512) * sizeof(float)
                    + (size_t)10 * 32768 * sizeof(short)
                    + ((size_t)3 * n3 + 1 + 1024 + (size_t)3 * E) * sizeof(int)
                    + 65536;  // slack for mm staging over-read
  if (ws_size < need_bytes) {
    fprintf(stderr, "kernel_launch: ws too small (%zu < %zu)\n", ws_size, need_bytes);
    return;
  }

  // JAX keys: dk = split(key(42), 4) (partitionable threefry, verified round 2)
  uint32_t dk[4][2];
  for (uint32_t i = 0; i < 4; ++i) tf2x32(0u, 42u, 0u, i, dk[i][0], dk[i][1]);

  WPack pk;
  auto U = [](const float* Wu, int t) { return Wu + (size_t)t * 32768; };
  auto L = [](const float* Wu, int t) { return Wu + (size_t)t * 32768 + 16384; };
  auto WH = [&](int m) { return wtsS + (size_t)m * 32768; };
  auto WL = [&](int m) { return wtsS + (size_t)m * 32768 + 16384; };
  const size_t MS = 128 * 128;
  pk.d[0] = { Wn1 + 0 * MS, U(Wu1, 0), nullptr, nullptr, WH(0), WL(0) };  // Cn0_1
  pk.d[1] = { Wn1 + 1 * MS, U(Wu1, 1), nullptr, nullptr, WH(1), WL(1) };  // Cn1_1
  pk.d[2] = { Wn1 + 2 * MS, U(Wu1, 2), nullptr, nullptr, WH(2), WL(2) };  // Cn2_1
  pk.d[3] = { Ws1 + 0 * MS, L(Wu1, 0), Ws1 + 2 * MS, L(Wu1, 2), WH(3), WL(3) };  // CsA1
  pk.d[4] = { Ws1 + 1 * MS, L(Wu1, 1), nullptr, nullptr, WH(4), WL(4) };  // CsB1
  pk.d[5] = { Wn2 + 0 * MS, U(Wu2, 0), nullptr, nullptr, WH(5), WL(5) };  // Cn0_2
  pk.d[6] = { Wn2 + 1 * MS, U(Wu2, 1), nullptr, nullptr, WH(6), WL(6) };  // Cn1_2
  pk.d[7] = { Wn2 + 2 * MS, U(Wu2, 2), nullptr, nullptr, WH(7), WL(7) };  // Cn2_2
  pk.d[8] = { Ws2 + 0 * MS, L(Wu2, 0), Ws2 + 2 * MS, L(Wu2, 2), WH(8), WL(8) };  // CsA2
  pk.d[9] = { Ws2 + 1 * MS, L(Wu2, 1), nullptr, nullptr, WH(9), WL(9) };  // CsB2

  const int gdrop = (int)((nh / 2 + 255) / 256);
  const int gE    = (E + 255) / 256;
  const int gmm   = (n + 127) / 128;
  const int gga   = (n * 64 + 255) / 256;
  const int nbA   = (n3 + 1023) / 1024;

  // ---- CSR build ----
  hipMemsetAsync(cnt, 0, (size_t)n3 * sizeof(int), stream);
  k_count<<<gE, 256, 0, stream>>>(ei0, cnt, E);
  k_count<<<gE, 256, 0, stream>>>(ei1, cnt + n, E);
  k_count<<<gE, 256, 0, stream>>>(ei2, cnt + 2 * n, E);
  k_scanA<<<nbA, 256, 0, stream>>>(cnt, off, bsum, n3);
  k_scanB<<<1, 256, 0, stream>>>(bsum, nbA, off, n3);
  k_scanC<<<(n3 + 255) / 256, 256, 0, stream>>>(off, bsum, cur, n3);
  k_fill<<<gE, 256, 0, stream>>>(ei0, cur, srcl, E);
  k_fill<<<gE, 256, 0, stream>>>(ei1, cur + n, srcl, E);
  k_fill<<<gE, 256, 0, stream>>>(ei2, cur + 2 * n, srcl, E);

  // ---- weights / biases ----
  k_wprec<<<40, 256, 0, stream>>>(pk);
  k_bias<<<1, 256, 0, stream>>>(bn1, bs1, bu1, Wu1, cbA1, cbB1);
  k_bias<<<1, 256, 0, stream>>>(bn2, bs2, bu2, Wu2, cbA2, cbB2);

  // ---- input dropout+relu -> hi/lo ----
  k_drop_in<<<gdrop, 256, 0, stream>>>(xA, buf_hA, (int)(nh / 2), dk[0][0], dk[0][1]);
  k_drop_in<<<gdrop, 256, 0, stream>>>(xB, buf_hB, (int)(nh / 2), dk[1][0], dk[1][1]);

  // ---- layer 1 ----
  k_gather<<<gga, 256, 0, stream>>>(buf_hB, off + 2 * n, srcl, g2, n);   // ei2: B->A
  k_gather<<<gga, 256, 0, stream>>>(buf_hA, off + n, srcl, g1, n);       // ei1: A->B
  k_mmx<2, 1><<<gmm, 256, 0, stream>>>(g1, buf_hB, nullptr,
                                       WH(1), WL(1), WH(4), WL(4), nullptr, nullptr,
                                       cbB1, buf_hB, n, dk[3][0], dk[3][1]);  // h2B (in place)
  k_gather<<<gga, 256, 0, stream>>>(buf_hA, off, srcl, g1, n);           // ei0: A->A
  k_mmx<3, 1><<<gmm, 256, 0, stream>>>(g1, g2, buf_hA,
                                       WH(0), WL(0), WH(2), WL(2), WH(3), WL(3),
                                       cbA1, buf_hA, n, dk[2][0], dk[2][1]);  // h2A (in place)

  // ---- layer 2 ----
  float* oA = (float*)d_out;
  float* oB = oA + nh;
  k_gather<<<gga, 256, 0, stream>>>(buf_hB, off + 2 * n, srcl, g2, n);   // ei2
  k_gather<<<gga, 256, 0, stream>>>(buf_hA, off + n, srcl, g1, n);       // ei1
  k_mmx<2, 0><<<gmm, 256, 0, stream>>>(g1, buf_hB, nullptr,
                                       WH(6), WL(6), WH(9), WL(9), nullptr, nullptr,
                                       cbB2, oB, n, 0u, 0u);
  k_gather<<<gga, 256, 0, stream>>>(buf_hA, off, srcl, g1, n);           // ei0
  k_mmx<3, 0><<<gmm, 256, 0, stream>>>(g1, g2, buf_hA,
                                       WH(5), WL(5), WH(7), WL(7), WH(8), WL(8),
                                       cbA2, oA, n, 0u, 0u);
}